// Round 14
// baseline (648.568 us; speedup 1.0000x reference)
//
#include <hip/hip_runtime.h>
#include <hip/hip_bf16.h>
#include <math.h>

#define N 4
#define C 256
#define H 128
#define W 128
#define CO 288        // GROUP * K * K = 32 * 9
#define OH 126
#define OW 126
#define GROUP 32
#define CPG 8
#define EPS 1e-5f

#define HW (OH*OW)          // 15876
#define XSLICE (H*W)        // 16384
#define XNSTRIDE (C*H*W)    // 4194304
#define SNSTRIDE (CO*HW)    // 4572288
#define LONSTRIDE (C*HW)    // 4064256
#define WSTRIDE (CO*256)    // 73728 u16 per shift s
#define WTOT (9*CO*256)     // 663552 u16 per table (wlT = whT + WTOT)
#define XTOT (N*H*W*C)      // 16777216 u16 per table (xl = xh + XTOT)

typedef unsigned short u16;
typedef __attribute__((ext_vector_type(8))) short short8;
typedef __attribute__((ext_vector_type(4))) float float4v;

__device__ inline u16 f2bf(float v) {
    __hip_bfloat16 b = __float2bfloat16(v);
    return __builtin_bit_cast(u16, b);
}
__device__ inline float bf2f(u16 u) {
    __hip_bfloat16 b = __builtin_bit_cast(__hip_bfloat16, u);
    return __bfloat162float(b);
}

// ---------------- Prep: split x into bf16 hi/lo, transpose to NHWC ----------------
// xh/xl layout: [n][h][w][ci] (ci contiguous); xl MUST be at xh + XTOT.
__global__ __launch_bounds__(256) void split_x_kernel(const float* __restrict__ x,
                                                      u16* __restrict__ xh,
                                                      u16* __restrict__ xl) {
    const int ci = threadIdx.x;          // 0..255
    const int w0 = blockIdx.x * 8;       // 16 groups
    const int h  = blockIdx.y;
    const int n  = blockIdx.z;
    const float* src = x + ((size_t)(n*C + ci)*H + h)*W + w0;
    float4 v0 = *(const float4*)src;
    float4 v1 = *(const float4*)(src + 4);
    float vals[8] = {v0.x, v0.y, v0.z, v0.w, v1.x, v1.y, v1.z, v1.w};
    size_t obase = ((size_t)(n*H + h)*W + w0)*C + ci;
    #pragma unroll
    for (int dw = 0; dw < 8; ++dw) {
        float v = vals[dw];
        u16 hb = f2bf(v);
        xh[obase + (size_t)dw*C] = hb;
        xl[obase + (size_t)dw*C] = f2bf(v - bf2f(hb));
    }
}

// ---------------- Prep: split w into bf16 hi/lo, layout [s][co][ci] ----------------
__global__ __launch_bounds__(256) void split_w_kernel(const float* __restrict__ wgt,
                                                      u16* __restrict__ whT,
                                                      u16* __restrict__ wlT) {
    const int i = blockIdx.x*256 + threadIdx.x;  // < 9*288*256 = 663552
    const int ci = i & 255;
    const int co = (i >> 8) % CO;
    const int s  = i / (CO*256);
    float v = wgt[(size_t)co*(C*9) + (size_t)ci*9 + s];
    u16 hb = f2bf(v);
    whT[i] = hb;
    wlT[i] = f2bf(v - bf2f(hb));
}

// ---------------- Conv 3x3 VALID via bf16 MFMA implicit GEMM ----------------
// Round-14: counted-vmcnt (T4) with HALF-SHIFT windows and LDS back under the
// proven 124928-B threshold (r13's 161792-B full-shift variant killed the
// container twice; LDS footprint is the prime suspect, so the same experiment
// is re-run at 106496 B).
//
// Grid (2, 32, N) = 256 blocks = 1 block/CU, 512 threads = 8 waves.
// Window u = one w-split (hi or lo of shift s): bh-window = 72 MFMA/wave,
// bl-window = 36 MFMA/wave (exactly r4's verified unit split; ah/al fragments
// loaded in the bh-window, ah reused in the bl-window).
// 3 half-shift w-buffers (3 x 18432 B): window u reads buf br = u%3, stages
// split(u+2) into buf (br+2)%3, ends with `s_waitcnt vmcnt(w_n)` -- leaves the
// just-issued stage in flight, guarantees split(u+1) landed -- then
// lgkmcnt(0) + RAW s_barrier (no compiler vmem drain). The lgkmcnt(0) before
// each barrier also retires this window's ds_reads so the next window may
// overwrite the buffer it read. Buffer rotation: B(s) writes the buffer A(s)
// just consumed. Counted waits hold even across the ci0 boundary; only the
// last two windows (no further staging) drain vmcnt to 0. The s==8 xs-restage
// keeps a lgkm-only mid-fence; its loads age ~2 windows before first use.
// MFMA order per acc element identical to r4/r11/r12 -> sigma bitwise identical.
// LDS: 51200 (xs) + 55296 (wsh) = 106496 B <= 124928 proven.
__global__ __launch_bounds__(512, 2) void conv_mfma_kernel(const u16* __restrict__ xh,
                                                           const u16* __restrict__ whT,
                                                           float* __restrict__ sigma) {
    // xs chunk c = spq*396 + row*66 + col (spq = sp*4+q, row 0..5, col 0..65)
    __shared__ __align__(16) u16 xs[25600];          // 51200 B
    // wsh buf b (half-shift, one split): chunk c = q*288 + co ; idx = b*9216 + c*8
    __shared__ __align__(16) u16 wsh[3*9216];        // 55296 B (total 106496 B)

    const int tid  = threadIdx.x;
    const int wave = tid >> 6;
    const int lane = tid & 63;
    const int m16  = lane & 15;
    const int q    = lane >> 4;
    const int wr   = wave & 3;      // output row within block (0..3)
    const int wc   = wave >> 2;     // co half (144 each)
    const int ow0  = blockIdx.x * 64;
    const int oh0  = blockIdx.y * 4;
    const int n    = blockIdx.z;

    // ---- w staging: 1152 chunks per split-window; waves issue 3/3/2/2/2/2/2/2 ----
    const int w_n    = (wave < 2) ? 3 : 2;
    const int w_base = (wave < 2) ? wave*192 : 384 + (wave-2)*128;
    int wsrc[3];
    #pragma unroll
    for (int i = 0; i < 3; ++i) {
        int c = w_base + i*64 + lane;
        if (c > 1151) c = 1151;                  // only reached by unused issues
        const int cq  = c / 288;
        const int cco = c - cq*288;
        wsrc[i] = cco*256 + cq*8;                // + split*WTOT + s*WSTRIDE + ci0
    }

    // ---- x staging: 3168 chunks; issue idx = 8t+wave, t<7 (t==6 only wave<2) ----
    int xoff[7];
    #pragma unroll
    for (int t = 0; t < 7; ++t) {
        int c = (8*t + wave)*64 + lane;
        if (c > 3167) c = 3167;                  // pad tail: source clamped, dest in pad
        const int spq = c / 396;
        const int rem = c - spq*396;
        const int row = rem / 66;
        const int col = rem - row*66;
        int gr = oh0 + row; if (gr > H-1) gr = H-1;   // clamp feeds discarded outputs
        int gc = ow0 + col; if (gc > W-1) gc = W-1;
        xoff[t] = (spq >> 2)*XTOT + ((n*H + gr)*W + gc)*C + (spq & 3)*8;
    }

    // ---- fragment read offsets (u16 units) ----
    const int aoff = (q*396 + wr*66 + m16)*8;    // + (ky*66+kx)*8 + mt*128 ; lo +12672
    const int boff = (q*288 + wc*144 + m16)*8;   // + b*9216 + j*128

    float4v acc[4][9];
    #pragma unroll
    for (int mt = 0; mt < 4; ++mt)
        #pragma unroll
        for (int j = 0; j < 9; ++j) acc[mt][j] = (float4v)(0.f);

    // ---- prologue: stage xs(ci0=0); hi(0)->buf0; lo(0)->buf1 ----
    #pragma unroll
    for (int t = 0; t < 7; ++t)
        if (t < 6 || wave < 2)
            __builtin_amdgcn_global_load_lds((const uint*)(xh + xoff[t]),
                                             (uint*)(xs + (8*t + wave)*512), 16, 0, 0);
    #pragma unroll
    for (int i = 0; i < 3; ++i)
        if (i < w_n)
            __builtin_amdgcn_global_load_lds((const uint*)(whT + wsrc[i]),
                                             (uint*)(wsh + (w_base + i*64)*8), 16, 0, 0);
    #pragma unroll
    for (int i = 0; i < 3; ++i)
        if (i < w_n)
            __builtin_amdgcn_global_load_lds((const uint*)(whT + WTOT + wsrc[i]),
                                             (uint*)(wsh + 9216 + (w_base + i*64)*8), 16, 0, 0);
    // wait until xs + hi(0) landed (lo(0) stays in flight), then publish
    if (wave < 2) asm volatile("s_waitcnt vmcnt(3)" ::: "memory");
    else          asm volatile("s_waitcnt vmcnt(2)" ::: "memory");
    __builtin_amdgcn_s_barrier();

    int br = 0;                      // read-buffer for current window
    for (int ci0 = 0; ci0 < C; ci0 += 32) {
        const int nci = ci0 + 32;
        #pragma unroll 1
        for (int s = 0; s < 9; ++s) {
            const int ky = s / 3;
            const int kx = s - 3*ky;

            // ================= window A (bh): 72 MFMA =================
            {   // stage hi(s+1) [or hi(0) of next ci0] into (br+2)%3
                const int bw = (br + 2 >= 3) ? br - 1 : br + 2;
                if (s < 8) {
                    const int soff = (s+1)*WSTRIDE + ci0;
                    #pragma unroll
                    for (int i = 0; i < 3; ++i)
                        if (i < w_n)
                            __builtin_amdgcn_global_load_lds(
                                (const uint*)(whT + soff + wsrc[i]),
                                (uint*)(wsh + bw*9216 + (w_base + i*64)*8), 16, 0, 0);
                } else if (nci < C) {
                    #pragma unroll
                    for (int i = 0; i < 3; ++i)
                        if (i < w_n)
                            __builtin_amdgcn_global_load_lds(
                                (const uint*)(whT + nci + wsrc[i]),
                                (uint*)(wsh + bw*9216 + (w_base + i*64)*8), 16, 0, 0);
                }
            }
            const int ab = aoff + (ky*66 + kx)*8;
            short8 ah0 = *(const short8*)&xs[ab];
            short8 ah1 = *(const short8*)&xs[ab + 128];
            short8 ah2 = *(const short8*)&xs[ab + 256];
            short8 ah3 = *(const short8*)&xs[ab + 384];
            short8 al0 = *(const short8*)&xs[ab + 12672];
            short8 al1 = *(const short8*)&xs[ab + 12672 + 128];
            short8 al2 = *(const short8*)&xs[ab + 12672 + 256];
            short8 al3 = *(const short8*)&xs[ab + 12672 + 384];

            if (s == 8) {
                // last xs reads of this ci0 retired -> raw fence (NO vmem
                // drain), then issue next ci0's xs; they age ~2 windows.
                asm volatile("s_waitcnt lgkmcnt(0)" ::: "memory");
                __builtin_amdgcn_s_barrier();
                if (nci < C) {
                    #pragma unroll
                    for (int t = 0; t < 7; ++t)
                        if (t < 6 || wave < 2)
                            __builtin_amdgcn_global_load_lds(
                                (const uint*)(xh + xoff[t] + nci),
                                (uint*)(xs + (8*t + wave)*512), 16, 0, 0);
                }
            }

            {
                const u16* wb = wsh + br*9216 + boff;
                __builtin_amdgcn_s_setprio(1);
                #pragma unroll
                for (int j = 0; j < 9; ++j) {
                    short8 bh = *(const short8*)&wb[j*128];
                    acc[0][j] = __builtin_amdgcn_mfma_f32_16x16x32_bf16(ah0, bh, acc[0][j], 0, 0, 0);
                    acc[1][j] = __builtin_amdgcn_mfma_f32_16x16x32_bf16(ah1, bh, acc[1][j], 0, 0, 0);
                    acc[2][j] = __builtin_amdgcn_mfma_f32_16x16x32_bf16(ah2, bh, acc[2][j], 0, 0, 0);
                    acc[3][j] = __builtin_amdgcn_mfma_f32_16x16x32_bf16(ah3, bh, acc[3][j], 0, 0, 0);
                    acc[0][j] = __builtin_amdgcn_mfma_f32_16x16x32_bf16(al0, bh, acc[0][j], 0, 0, 0);
                    acc[1][j] = __builtin_amdgcn_mfma_f32_16x16x32_bf16(al1, bh, acc[1][j], 0, 0, 0);
                    acc[2][j] = __builtin_amdgcn_mfma_f32_16x16x32_bf16(al2, bh, acc[2][j], 0, 0, 0);
                    acc[3][j] = __builtin_amdgcn_mfma_f32_16x16x32_bf16(al3, bh, acc[3][j], 0, 0, 0);
                }
                __builtin_amdgcn_s_setprio(0);
            }
            // end of window A: counted wait
            if (s == 8) {
                if (nci < C) {
                    // outstanding: lo(8) + hi(0,nci) + xs(nci); need lo(8)
                    if (wave < 2) asm volatile("s_waitcnt vmcnt(10)" ::: "memory");
                    else          asm volatile("s_waitcnt vmcnt(8)"  ::: "memory");
                } else {
                    asm volatile("s_waitcnt vmcnt(0)" ::: "memory");
                }
            } else {
                if (wave < 2) asm volatile("s_waitcnt vmcnt(3)" ::: "memory");
                else          asm volatile("s_waitcnt vmcnt(2)" ::: "memory");
            }
            asm volatile("s_waitcnt lgkmcnt(0)" ::: "memory");
            __builtin_amdgcn_s_barrier();
            br = (br + 1 >= 3) ? 0 : br + 1;

            // ================= window B (bl): 36 MFMA =================
            {   // stage lo(s+1) [or lo(0) of next ci0] into (br+2)%3
                const int bw = (br + 2 >= 3) ? br - 1 : br + 2;
                if (s < 8) {
                    const int soff = WTOT + (s+1)*WSTRIDE + ci0;
                    #pragma unroll
                    for (int i = 0; i < 3; ++i)
                        if (i < w_n)
                            __builtin_amdgcn_global_load_lds(
                                (const uint*)(whT + soff + wsrc[i]),
                                (uint*)(wsh + bw*9216 + (w_base + i*64)*8), 16, 0, 0);
                } else if (nci < C) {
                    #pragma unroll
                    for (int i = 0; i < 3; ++i)
                        if (i < w_n)
                            __builtin_amdgcn_global_load_lds(
                                (const uint*)(whT + WTOT + nci + wsrc[i]),
                                (uint*)(wsh + bw*9216 + (w_base + i*64)*8), 16, 0, 0);
                }
            }
            {
                const u16* wb = wsh + br*9216 + boff;
                __builtin_amdgcn_s_setprio(1);
                #pragma unroll
                for (int j = 0; j < 9; ++j) {
                    short8 bl = *(const short8*)&wb[j*128];
                    acc[0][j] = __builtin_amdgcn_mfma_f32_16x16x32_bf16(ah0, bl, acc[0][j], 0, 0, 0);
                    acc[1][j] = __builtin_amdgcn_mfma_f32_16x16x32_bf16(ah1, bl, acc[1][j], 0, 0, 0);
                    acc[2][j] = __builtin_amdgcn_mfma_f32_16x16x32_bf16(ah2, bl, acc[2][j], 0, 0, 0);
                    acc[3][j] = __builtin_amdgcn_mfma_f32_16x16x32_bf16(ah3, bl, acc[3][j], 0, 0, 0);
                }
                __builtin_amdgcn_s_setprio(0);
            }
            // end of window B: counted wait (drains hi(next) + xs; leaves lo(next))
            if (s == 8 && nci >= C) {
                asm volatile("s_waitcnt vmcnt(0)" ::: "memory");
            } else {
                if (wave < 2) asm volatile("s_waitcnt vmcnt(3)" ::: "memory");
                else          asm volatile("s_waitcnt vmcnt(2)" ::: "memory");
            }
            asm volatile("s_waitcnt lgkmcnt(0)" ::: "memory");
            __builtin_amdgcn_s_barrier();
            br = (br + 1 >= 3) ? 0 : br + 1;
        }
    }

    // store: D[row=q*4+r][col=m16]; pos = mt*16+q*4+r, co = wc*144+j*16+m16
    const int oh = oh0 + wr;
    if (oh < OH) {
        #pragma unroll
        for (int mt = 0; mt < 4; ++mt) {
            const int posb = mt*16 + q*4;
            #pragma unroll
            for (int j = 0; j < 9; ++j) {
                const int co = wc*144 + j*16 + m16;
                float* dst = sigma + (size_t)n*SNSTRIDE + (size_t)co*HW + oh*OW;
                #pragma unroll
                for (int r = 0; r < 4; ++r) {
                    const int ow = ow0 + posb + r;
                    if (ow < OW) dst[ow] = acc[mt][j][r];
                }
            }
        }
    }
}

// ---------------- Per-channel mean/var over (N, OH, OW) ----------------
__global__ __launch_bounds__(1024) void stats_kernel(const float* __restrict__ sigma,
                                                     const float* __restrict__ gamma,
                                                     const float* __restrict__ beta,
                                                     float* __restrict__ coef) {
    const int c = blockIdx.x;
    float sum = 0.f, sq = 0.f;
    for (int n = 0; n < N; ++n) {
        const float* sp = sigma + (size_t)n*SNSTRIDE + (size_t)c*HW;
        for (int i = threadIdx.x; i < HW; i += 1024) {
            float v = sp[i];
            sum += v; sq += v * v;
        }
    }
    for (int off = 32; off > 0; off >>= 1) {
        sum += __shfl_down(sum, off, 64);
        sq  += __shfl_down(sq,  off, 64);
    }
    __shared__ float ls[16], lq[16];
    const int wid = threadIdx.x >> 6, lane = threadIdx.x & 63;
    if (lane == 0) { ls[wid] = sum; lq[wid] = sq; }
    __syncthreads();
    if (threadIdx.x == 0) {
        float S = 0.f, Q = 0.f;
        #pragma unroll
        for (int i = 0; i < 16; ++i) { S += ls[i]; Q += lq[i]; }
        const float cnt = (float)(N * HW);
        float mean = S / cnt;
        float var  = Q / cnt - mean * mean;
        float a = gamma[c] * rsqrtf(var + EPS);
        coef[c]      = a;
        coef[CO + c] = beta[c] - mean * a;
    }
}

// ---------------- Fused normalize + softmax(288) + grouped dynamic 3x3 ----------------
// LDS-staged x (r12, verified): one block per (n, oh) row, 512 threads; per
// group g the 8ch x 3row x 128 slab is staged double-buffered with coalesced
// float4 loads; thread (pos, gc) computes 2 channels from LDS.
__global__ __launch_bounds__(512) void fuse_kernel(const float* __restrict__ x,
                                                   const float* __restrict__ sigma,
                                                   const float* __restrict__ coef,
                                                   float* __restrict__ outlo,
                                                   float* __restrict__ sums) {
    __shared__ float a[CO], b[CO];
    __shared__ float xbuf[2][8*3*128];           // 2 x 12288 B (+ a/b = 27 KB)

    const int tid = threadIdx.x;
    for (int i = tid; i < CO; i += 512) {
        a[i] = coef[i];
        b[i] = coef[CO + i];
    }

    const int oh = blockIdx.x % OH;
    const int n  = blockIdx.x / OH;
    const float* xrow = x + (size_t)n * XNSTRIDE + (size_t)oh * W;

    // stage group g's slab: rows (ch*3+r) of 128 f32; 768 float4 chunks total
    const int f0row = tid >> 5, f0w4 = tid & 31;                 // f = tid (<512)
    const int f1row = (512 + tid) >> 5, f1w4 = tid & 31;         // f = 512+tid (tid<256)

    const int pos = tid >> 2;        // 0..127 (active < 126)
    const int gc  = tid & 3;         // channel pair selector
    const bool act = pos < OW;
    const int hw = oh * OW + pos;
    const float* sp = sigma + (size_t)n * SNSTRIDE + hw;
    float* ob = outlo + (size_t)n * LONSTRIDE + hw;

    // prologue: stage g=0 into buf 0
    {
        const float* src = xrow;     // g = 0
        const int ch = f0row / 3, r = f0row - 3*ch;
        *(float4*)&xbuf[0][f0row*128 + f0w4*4] =
            *(const float4*)(src + (size_t)ch*XSLICE + r*W + f0w4*4);
        if (tid < 256) {
            const int ch1 = f1row / 3, r1 = f1row - 3*ch1;
            *(float4*)&xbuf[0][f1row*128 + f1w4*4] =
                *(const float4*)(src + (size_t)ch1*XSLICE + r1*W + f1w4*4);
        }
    }
    __syncthreads();                 // xbuf[0] + a/b ready

    float sum = 0.f;
    int buf = 0;
    for (int g = 0; g < GROUP; ++g) {
        if (g + 1 < GROUP) {         // stage g+1 into buf^1 (no readers yet)
            const float* src = xrow + (size_t)((g+1)*CPG)*XSLICE;
            const int ch = f0row / 3, r = f0row - 3*ch;
            *(float4*)&xbuf[buf^1][f0row*128 + f0w4*4] =
                *(const float4*)(src + (size_t)ch*XSLICE + r*W + f0w4*4);
            if (tid < 256) {
                const int ch1 = f1row / 3, r1 = f1row - 3*ch1;
                *(float4*)&xbuf[buf^1][f1row*128 + f1w4*4] =
                    *(const float4*)(src + (size_t)ch1*XSLICE + r1*W + f1w4*4);
            }
        }
        if (act) {
            float acc0 = 0.f, acc1 = 0.f;
            #pragma unroll
            for (int p = 0; p < 9; ++p) {
                const int ch = g * 9 + p;
                float s = sp[(size_t)ch * HW] * a[ch] + b[ch];
                float e = __expf(s);
                sum += e;
                const int r = p / 3, cx = p - 3*r;
                const int w = pos + cx;          // <= 127, in-slab
                acc0 += xbuf[buf][((gc*2 + 0)*3 + r)*128 + w] * e;
                acc1 += xbuf[buf][((gc*2 + 1)*3 + r)*128 + w] * e;
            }
            ob[(size_t)(g*CPG + gc*2 + 0) * HW] = acc0;
            ob[(size_t)(g*CPG + gc*2 + 1) * HW] = acc1;
        }
        __syncthreads();             // buf readers done; buf^1 writes visible
        buf ^= 1;
    }
    if (act && gc == 0) sums[(size_t)n * HW + hw] = sum;
}

// ---------------- Bilinear align-corners upsample 126 -> 128 (+ softmax divide) ----
__global__ __launch_bounds__(256) void upsample_kernel(const float* __restrict__ lo,
                                                       const float* __restrict__ sums,
                                                       float* __restrict__ out) {
    const int idx = blockIdx.x * 256 + threadIdx.x;
    const int xi = idx & (W - 1);
    const int yi = (idx >> 7) & (H - 1);
    const int nc = idx >> 14;
    const int n  = nc >> 8;              // C = 256

    const float scale = 125.0f / 127.0f;
    const float sy = yi * scale;
    const float sx = xi * scale;
    int y0 = (int)sy;
    int x0 = (int)sx;
    float wy = sy - (float)y0;
    float wx = sx - (float)x0;
    int y1 = min(y0 + 1, OH - 1);
    int x1 = min(x0 + 1, OW - 1);

    const float* p  = lo + (size_t)nc * HW;
    const float* ps = sums + (size_t)n * HW;
    float v00 = p[y0 * OW + x0] / ps[y0 * OW + x0];
    float v01 = p[y0 * OW + x1] / ps[y0 * OW + x1];
    float v10 = p[y1 * OW + x0] / ps[y1 * OW + x0];
    float v11 = p[y1 * OW + x1] / ps[y1 * OW + x1];
    float top = v00 * (1.f - wx) + v01 * wx;
    float bot = v10 * (1.f - wx) + v11 * wx;
    out[idx] = top * (1.f - wy) + bot * wy;
}

extern "C" void kernel_launch(void* const* d_in, const int* in_sizes, int n_in,
                              void* d_out, int out_size, void* d_ws, size_t ws_size,
                              hipStream_t stream) {
    const float* x      = (const float*)d_in[0];
    const float* conv_w = (const float*)d_in[1];
    const float* gamma  = (const float*)d_in[2];
    const float* beta   = (const float*)d_in[3];
    float* out = (float*)d_out;
    float* ws  = (float*)d_ws;

    // workspace (floats):
    //   sigma : [0, 18289152)
    //   coef  : [18289152, +1024)
    //   outlo : [18290176, +16257024)   -- ALIASED with xh/xl (prep+conv finish first)
    //   sums  : aliased over whT (dead after conv, written by fuse, read by upsample)
    float* sigma = ws;
    float* coef  = ws + 18289152;
    float* outlo = ws + 18290176;
    u16* xhp = (u16*)(ws + 18290176);               // 16777216 u16 = 33.5 MB
    u16* xlp = xhp + (size_t)XTOT;                  // adjacent: xl = xh + XTOT
    u16* whT = xlp + (size_t)XTOT;                  // 663552 u16
    u16* wlT = whT + (size_t)WTOT;                  // adjacent: wl = wh + WTOT
    float* sums = (float*)whT;                      // 63504 floats, fits in w region
    // total ws usage ~143 MB

    split_x_kernel<<<dim3(16, 128, 4), 256, 0, stream>>>(x, xhp, xlp);
    split_w_kernel<<<(9*CO*256)/256, 256, 0, stream>>>(conv_w, whT, wlT);

    conv_mfma_kernel<<<dim3(2, 32, N), 512, 0, stream>>>(xhp, whT, sigma);

    stats_kernel<<<CO, 1024, 0, stream>>>(sigma, gamma, beta, coef);

    fuse_kernel<<<N * OH, 512, 0, stream>>>(x, sigma, coef, outlo, sums);

    upsample_kernel<<<(N * C * H * W) / 256, 256, 0, stream>>>(outlo, sums, out);
}

// Round 15
// 549.990 us; speedup vs baseline: 1.1792x; 1.1792x over previous
//
#include <hip/hip_runtime.h>
#include <hip/hip_bf16.h>
#include <math.h>

#define N 4
#define C 256
#define H 128
#define W 128
#define CO 288        // GROUP * K * K = 32 * 9
#define OH 126
#define OW 126
#define GROUP 32
#define CPG 8
#define EPS 1e-5f

#define HW (OH*OW)          // 15876
#define XSLICE (H*W)        // 16384
#define XNSTRIDE (C*H*W)    // 4194304
#define SNSTRIDE (CO*HW)    // 4572288
#define LONSTRIDE (C*HW)    // 4064256
#define WSTRIDE (CO*256)    // 73728 u16 per shift s
#define WTOT (9*CO*256)     // 663552 u16 per table (wlT = whT + WTOT)
#define XTOT (N*H*W*C)      // 16777216 u16 per table (xl = xh + XTOT)

typedef unsigned short u16;
typedef __attribute__((ext_vector_type(8))) short short8;
typedef __attribute__((ext_vector_type(4))) float float4v;

__device__ inline u16 f2bf(float v) {
    __hip_bfloat16 b = __float2bfloat16(v);
    return __builtin_bit_cast(u16, b);
}
__device__ inline float bf2f(u16 u) {
    __hip_bfloat16 b = __builtin_bit_cast(__hip_bfloat16, u);
    return __bfloat162float(b);
}

// ---------------- Prep: split x into bf16 hi/lo, transpose to NHWC ----------------
// xh/xl layout: [n][h][w][ci] (ci contiguous); xl MUST be at xh + XTOT.
__global__ __launch_bounds__(256) void split_x_kernel(const float* __restrict__ x,
                                                      u16* __restrict__ xh,
                                                      u16* __restrict__ xl) {
    const int ci = threadIdx.x;          // 0..255
    const int w0 = blockIdx.x * 8;       // 16 groups
    const int h  = blockIdx.y;
    const int n  = blockIdx.z;
    const float* src = x + ((size_t)(n*C + ci)*H + h)*W + w0;
    float4 v0 = *(const float4*)src;
    float4 v1 = *(const float4*)(src + 4);
    float vals[8] = {v0.x, v0.y, v0.z, v0.w, v1.x, v1.y, v1.z, v1.w};
    size_t obase = ((size_t)(n*H + h)*W + w0)*C + ci;
    #pragma unroll
    for (int dw = 0; dw < 8; ++dw) {
        float v = vals[dw];
        u16 hb = f2bf(v);
        xh[obase + (size_t)dw*C] = hb;
        xl[obase + (size_t)dw*C] = f2bf(v - bf2f(hb));
    }
}

// ---------------- Prep: split w into bf16 hi/lo, layout [s][co][ci] ----------------
__global__ __launch_bounds__(256) void split_w_kernel(const float* __restrict__ wgt,
                                                      u16* __restrict__ whT,
                                                      u16* __restrict__ wlT) {
    const int i = blockIdx.x*256 + threadIdx.x;  // < 9*288*256 = 663552
    const int ci = i & 255;
    const int co = (i >> 8) % CO;
    const int s  = i / (CO*256);
    float v = wgt[(size_t)co*(C*9) + (size_t)ci*9 + s];
    u16 hb = f2bf(v);
    whT[i] = hb;
    wlT[i] = f2bf(v - bf2f(hb));
}

// ---------------- Conv 3x3 VALID via bf16 MFMA implicit GEMM ----------------
// VERBATIM round-11/12 (318 us, MfmaUtil 36%): one-barrier-per-shift, 1 block/CU,
// 512 threads, 4 rows x 64 pos x 288 co, full-shift wsh double-buffer.
// This is the structural ceiling of the 2-phase schedule family (m233): the
// T4 counted-vmcnt escapes were tried and failed -- full-shift 3-buffer
// (161 KB LDS) killed the container (r13); half-shift 3-buffer spilled
// (~280 MB scratch traffic, conv 410 us, r14). Conv arc closed.
__global__ __launch_bounds__(512, 2) void conv_mfma_kernel(const u16* __restrict__ xh,
                                                           const u16* __restrict__ whT,
                                                           float* __restrict__ sigma) {
    // xs chunk c = spq*396 + row*66 + col (spq = sp*4+q, row 0..5, col 0..65)
    __shared__ __align__(16) u16 xs[25600];          // 51200 B
    // wsh buf: chunk c = sp*1152 + q*288 + co ; u16 idx = buf*18432 + c*8
    __shared__ __align__(16) u16 wsh[2*18432];       // 73728 B  (total 124928 B)

    const int tid  = threadIdx.x;
    const int wave = tid >> 6;
    const int lane = tid & 63;
    const int m16  = lane & 15;
    const int q    = lane >> 4;
    const int wr   = wave & 3;      // output row within block (0..3)
    const int wc   = wave >> 2;     // co half (144 each)
    const int ow0  = blockIdx.x * 64;
    const int oh0  = blockIdx.y * 4;
    const int n    = blockIdx.z;

    // ---- w staging: 2304 chunks (both splits); wave issues 5/5/5/5/4/4/4/4 ----
    const int w_n    = (wave < 4) ? 5 : 4;
    const int w_base = (wave < 4) ? wave*320 : 1280 + (wave-4)*256;
    int wsrc[5];
    #pragma unroll
    for (int i = 0; i < 5; ++i) {
        int c = w_base + i*64 + lane;            // < 2304 by construction
        const int sp  = c / 1152;
        const int rem = c - sp*1152;
        const int qc  = rem / 288;
        const int co  = rem - qc*288;
        wsrc[i] = sp*WTOT + co*256 + qc*8;       // + s*WSTRIDE + ci0
    }

    // ---- x staging: 3168 chunks; issue idx = 8t+wave, t<7 (t==6 only wave<2) ----
    int xoff[7];
    #pragma unroll
    for (int t = 0; t < 7; ++t) {
        int c = (8*t + wave)*64 + lane;
        if (c > 3167) c = 3167;                  // pad tail: source clamped, dest in pad
        const int spq = c / 396;
        const int rem = c - spq*396;
        const int row = rem / 66;
        const int col = rem - row*66;
        int gr = oh0 + row; if (gr > H-1) gr = H-1;   // clamp feeds discarded outputs
        int gc = ow0 + col; if (gc > W-1) gc = W-1;
        xoff[t] = (spq >> 2)*XTOT + ((n*H + gr)*W + gc)*C + (spq & 3)*8;
    }

    // ---- fragment read offsets (u16 units) ----
    const int aoff = (q*396 + wr*66 + m16)*8;    // + (ky*66+kx)*8 + mt*128 ; lo +12672
    const int boff = (q*288 + wc*144 + m16)*8;   // + buf*18432 + j*128 ; lo +9216

    float4v acc[4][9];
    #pragma unroll
    for (int mt = 0; mt < 4; ++mt)
        #pragma unroll
        for (int j = 0; j < 9; ++j) acc[mt][j] = (float4v)(0.f);

    // ---- prologue: stage xs(ci0=0) and w(s=0, ci0=0, both splits) into buf 0 ----
    #pragma unroll
    for (int t = 0; t < 7; ++t)
        if (t < 6 || wave < 2)
            __builtin_amdgcn_global_load_lds((const uint*)(xh + xoff[t]),
                                             (uint*)(xs + (8*t + wave)*512), 16, 0, 0);
    #pragma unroll
    for (int i = 0; i < 5; ++i)
        if (i < w_n)
            __builtin_amdgcn_global_load_lds((const uint*)(whT + wsrc[i]),
                                             (uint*)(wsh + (w_base + i*64)*8), 16, 0, 0);
    __syncthreads();

    int buf = 0;
    for (int ci0 = 0; ci0 < C; ci0 += 32) {
        #pragma unroll 1
        for (int s = 0; s < 9; ++s) {
            // stage next shift (same ci0) into buf^1 -- ages through this compute
            if (s < 8) {
                const int soff = (s+1)*WSTRIDE + ci0;
                #pragma unroll
                for (int i = 0; i < 5; ++i)
                    if (i < w_n)
                        __builtin_amdgcn_global_load_lds(
                            (const uint*)(whT + soff + wsrc[i]),
                            (uint*)(wsh + ((buf^1)*18432 + (w_base + i*64)*8)), 16, 0, 0);
            }

            const int ky = s / 3;
            const int kx = s - 3*ky;
            const int ab = aoff + (ky*66 + kx)*8;
            short8 ah0 = *(const short8*)&xs[ab];
            short8 ah1 = *(const short8*)&xs[ab + 128];
            short8 ah2 = *(const short8*)&xs[ab + 256];
            short8 ah3 = *(const short8*)&xs[ab + 384];
            short8 al0 = *(const short8*)&xs[ab + 12672];
            short8 al1 = *(const short8*)&xs[ab + 12672 + 128];
            short8 al2 = *(const short8*)&xs[ab + 12672 + 256];
            short8 al3 = *(const short8*)&xs[ab + 12672 + 384];

            if (s == 8) {
                // all waves' xs reads (above) complete at this fence; nothing
                // else outstanding -> cheap barrier. Then restage xs + w(0,nci)
                // into buf^1; both drain at this shift's ending barrier after
                // aging the full MFMA phase.
                __syncthreads();
                const int nci = ci0 + 32;
                if (nci < C) {
                    #pragma unroll
                    for (int t = 0; t < 7; ++t)
                        if (t < 6 || wave < 2)
                            __builtin_amdgcn_global_load_lds(
                                (const uint*)(xh + xoff[t] + nci),
                                (uint*)(xs + (8*t + wave)*512), 16, 0, 0);
                    #pragma unroll
                    for (int i = 0; i < 5; ++i)
                        if (i < w_n)
                            __builtin_amdgcn_global_load_lds(
                                (const uint*)(whT + nci + wsrc[i]),
                                (uint*)(wsh + ((buf^1)*18432 + (w_base + i*64)*8)), 16, 0, 0);
                }
            }

            const u16* wb = wsh + buf*18432 + boff;
            __builtin_amdgcn_s_setprio(1);
            #pragma unroll
            for (int j = 0; j < 9; ++j) {        // pass 1: bh (ah then al)
                short8 bh = *(const short8*)&wb[j*128];
                acc[0][j] = __builtin_amdgcn_mfma_f32_16x16x32_bf16(ah0, bh, acc[0][j], 0, 0, 0);
                acc[1][j] = __builtin_amdgcn_mfma_f32_16x16x32_bf16(ah1, bh, acc[1][j], 0, 0, 0);
                acc[2][j] = __builtin_amdgcn_mfma_f32_16x16x32_bf16(ah2, bh, acc[2][j], 0, 0, 0);
                acc[3][j] = __builtin_amdgcn_mfma_f32_16x16x32_bf16(ah3, bh, acc[3][j], 0, 0, 0);
                acc[0][j] = __builtin_amdgcn_mfma_f32_16x16x32_bf16(al0, bh, acc[0][j], 0, 0, 0);
                acc[1][j] = __builtin_amdgcn_mfma_f32_16x16x32_bf16(al1, bh, acc[1][j], 0, 0, 0);
                acc[2][j] = __builtin_amdgcn_mfma_f32_16x16x32_bf16(al2, bh, acc[2][j], 0, 0, 0);
                acc[3][j] = __builtin_amdgcn_mfma_f32_16x16x32_bf16(al3, bh, acc[3][j], 0, 0, 0);
            }
            #pragma unroll
            for (int j = 0; j < 9; ++j) {        // pass 2: bl (ah only)
                short8 bl = *(const short8*)&wb[9216 + j*128];
                acc[0][j] = __builtin_amdgcn_mfma_f32_16x16x32_bf16(ah0, bl, acc[0][j], 0, 0, 0);
                acc[1][j] = __builtin_amdgcn_mfma_f32_16x16x32_bf16(ah1, bl, acc[1][j], 0, 0, 0);
                acc[2][j] = __builtin_amdgcn_mfma_f32_16x16x32_bf16(ah2, bl, acc[2][j], 0, 0, 0);
                acc[3][j] = __builtin_amdgcn_mfma_f32_16x16x32_bf16(ah3, bl, acc[3][j], 0, 0, 0);
            }
            __builtin_amdgcn_s_setprio(0);

            __syncthreads();   // buf readers done; buf^1 loads drained (aged full shift)
            buf ^= 1;
        }
    }

    // store: D[row=q*4+r][col=m16]; pos = mt*16+q*4+r, co = wc*144+j*16+m16
    const int oh = oh0 + wr;
    if (oh < OH) {
        #pragma unroll
        for (int mt = 0; mt < 4; ++mt) {
            const int posb = mt*16 + q*4;
            #pragma unroll
            for (int j = 0; j < 9; ++j) {
                const int co = wc*144 + j*16 + m16;
                float* dst = sigma + (size_t)n*SNSTRIDE + (size_t)co*HW + oh*OW;
                #pragma unroll
                for (int r = 0; r < 4; ++r) {
                    const int ow = ow0 + posb + r;
                    if (ow < OW) dst[ow] = acc[mt][j][r];
                }
            }
        }
    }
}

// ---------------- Per-channel mean/var over (N, OH, OW) ----------------
__global__ __launch_bounds__(1024) void stats_kernel(const float* __restrict__ sigma,
                                                     const float* __restrict__ gamma,
                                                     const float* __restrict__ beta,
                                                     float* __restrict__ coef) {
    const int c = blockIdx.x;
    float sum = 0.f, sq = 0.f;
    for (int n = 0; n < N; ++n) {
        const float* sp = sigma + (size_t)n*SNSTRIDE + (size_t)c*HW;
        for (int i = threadIdx.x; i < HW; i += 1024) {
            float v = sp[i];
            sum += v; sq += v * v;
        }
    }
    for (int off = 32; off > 0; off >>= 1) {
        sum += __shfl_down(sum, off, 64);
        sq  += __shfl_down(sq,  off, 64);
    }
    __shared__ float ls[16], lq[16];
    const int wid = threadIdx.x >> 6, lane = threadIdx.x & 63;
    if (lane == 0) { ls[wid] = sum; lq[wid] = sq; }
    __syncthreads();
    if (threadIdx.x == 0) {
        float S = 0.f, Q = 0.f;
        #pragma unroll
        for (int i = 0; i < 16; ++i) { S += ls[i]; Q += lq[i]; }
        const float cnt = (float)(N * HW);
        float mean = S / cnt;
        float var  = Q / cnt - mean * mean;
        float a = gamma[c] * rsqrtf(var + EPS);
        coef[c]      = a;
        coef[CO + c] = beta[c] - mean * a;
    }
}

// ---------------- Fused normalize + softmax(288) + grouped dynamic 3x3 ----------------
// LDS-staged x (r12, verified): one block per (n, oh) row, 512 threads; per
// group g the 8ch x 3row x 128 slab is staged double-buffered with coalesced
// float4 loads; thread (pos, gc) computes 2 channels from LDS.
__global__ __launch_bounds__(512) void fuse_kernel(const float* __restrict__ x,
                                                   const float* __restrict__ sigma,
                                                   const float* __restrict__ coef,
                                                   float* __restrict__ outlo,
                                                   float* __restrict__ sums) {
    __shared__ float a[CO], b[CO];
    __shared__ float xbuf[2][8*3*128];           // 2 x 12288 B (+ a/b = 27 KB)

    const int tid = threadIdx.x;
    for (int i = tid; i < CO; i += 512) {
        a[i] = coef[i];
        b[i] = coef[CO + i];
    }

    const int oh = blockIdx.x % OH;
    const int n  = blockIdx.x / OH;
    const float* xrow = x + (size_t)n * XNSTRIDE + (size_t)oh * W;

    // stage group g's slab: rows (ch*3+r) of 128 f32; 768 float4 chunks total
    const int f0row = tid >> 5, f0w4 = tid & 31;                 // f = tid (<512)
    const int f1row = (512 + tid) >> 5, f1w4 = tid & 31;         // f = 512+tid (tid<256)

    const int pos = tid >> 2;        // 0..127 (active < 126)
    const int gc  = tid & 3;         // channel pair selector
    const bool act = pos < OW;
    const int hw = oh * OW + pos;
    const float* sp = sigma + (size_t)n * SNSTRIDE + hw;
    float* ob = outlo + (size_t)n * LONSTRIDE + hw;

    // prologue: stage g=0 into buf 0
    {
        const float* src = xrow;     // g = 0
        const int ch = f0row / 3, r = f0row - 3*ch;
        *(float4*)&xbuf[0][f0row*128 + f0w4*4] =
            *(const float4*)(src + (size_t)ch*XSLICE + r*W + f0w4*4);
        if (tid < 256) {
            const int ch1 = f1row / 3, r1 = f1row - 3*ch1;
            *(float4*)&xbuf[0][f1row*128 + f1w4*4] =
                *(const float4*)(src + (size_t)ch1*XSLICE + r1*W + f1w4*4);
        }
    }
    __syncthreads();                 // xbuf[0] + a/b ready

    float sum = 0.f;
    int buf = 0;
    for (int g = 0; g < GROUP; ++g) {
        if (g + 1 < GROUP) {         // stage g+1 into buf^1 (no readers yet)
            const float* src = xrow + (size_t)((g+1)*CPG)*XSLICE;
            const int ch = f0row / 3, r = f0row - 3*ch;
            *(float4*)&xbuf[buf^1][f0row*128 + f0w4*4] =
                *(const float4*)(src + (size_t)ch*XSLICE + r*W + f0w4*4);
            if (tid < 256) {
                const int ch1 = f1row / 3, r1 = f1row - 3*ch1;
                *(float4*)&xbuf[buf^1][f1row*128 + f1w4*4] =
                    *(const float4*)(src + (size_t)ch1*XSLICE + r1*W + f1w4*4);
            }
        }
        if (act) {
            float acc0 = 0.f, acc1 = 0.f;
            #pragma unroll
            for (int p = 0; p < 9; ++p) {
                const int ch = g * 9 + p;
                float s = sp[(size_t)ch * HW] * a[ch] + b[ch];
                float e = __expf(s);
                sum += e;
                const int r = p / 3, cx = p - 3*r;
                const int w = pos + cx;          // <= 127, in-slab
                acc0 += xbuf[buf][((gc*2 + 0)*3 + r)*128 + w] * e;
                acc1 += xbuf[buf][((gc*2 + 1)*3 + r)*128 + w] * e;
            }
            ob[(size_t)(g*CPG + gc*2 + 0) * HW] = acc0;
            ob[(size_t)(g*CPG + gc*2 + 1) * HW] = acc1;
        }
        __syncthreads();             // buf readers done; buf^1 writes visible
        buf ^= 1;
    }
    if (act && gc == 0) sums[(size_t)n * HW + hw] = sum;
}

// ---------------- Bilinear align-corners upsample 126 -> 128 (+ softmax divide) ----
__global__ __launch_bounds__(256) void upsample_kernel(const float* __restrict__ lo,
                                                       const float* __restrict__ sums,
                                                       float* __restrict__ out) {
    const int idx = blockIdx.x * 256 + threadIdx.x;
    const int xi = idx & (W - 1);
    const int yi = (idx >> 7) & (H - 1);
    const int nc = idx >> 14;
    const int n  = nc >> 8;              // C = 256

    const float scale = 125.0f / 127.0f;
    const float sy = yi * scale;
    const float sx = xi * scale;
    int y0 = (int)sy;
    int x0 = (int)sx;
    float wy = sy - (float)y0;
    float wx = sx - (float)x0;
    int y1 = min(y0 + 1, OH - 1);
    int x1 = min(x0 + 1, OW - 1);

    const float* p  = lo + (size_t)nc * HW;
    const float* ps = sums + (size_t)n * HW;
    float v00 = p[y0 * OW + x0] / ps[y0 * OW + x0];
    float v01 = p[y0 * OW + x1] / ps[y0 * OW + x1];
    float v10 = p[y1 * OW + x0] / ps[y1 * OW + x0];
    float v11 = p[y1 * OW + x1] / ps[y1 * OW + x1];
    float top = v00 * (1.f - wx) + v01 * wx;
    float bot = v10 * (1.f - wx) + v11 * wx;
    out[idx] = top * (1.f - wy) + bot * wy;
}

extern "C" void kernel_launch(void* const* d_in, const int* in_sizes, int n_in,
                              void* d_out, int out_size, void* d_ws, size_t ws_size,
                              hipStream_t stream) {
    const float* x      = (const float*)d_in[0];
    const float* conv_w = (const float*)d_in[1];
    const float* gamma  = (const float*)d_in[2];
    const float* beta   = (const float*)d_in[3];
    float* out = (float*)d_out;
    float* ws  = (float*)d_ws;

    // workspace (floats):
    //   sigma : [0, 18289152)
    //   coef  : [18289152, +1024)
    //   outlo : [18290176, +16257024)   -- ALIASED with xh/xl (prep+conv finish first)
    //   sums  : aliased over whT (dead after conv, written by fuse, read by upsample)
    float* sigma = ws;
    float* coef  = ws + 18289152;
    float* outlo = ws + 18290176;
    u16* xhp = (u16*)(ws + 18290176);               // 16777216 u16 = 33.5 MB
    u16* xlp = xhp + (size_t)XTOT;                  // adjacent: xl = xh + XTOT
    u16* whT = xlp + (size_t)XTOT;                  // 663552 u16
    u16* wlT = whT + (size_t)WTOT;                  // adjacent: wl = wh + WTOT
    float* sums = (float*)whT;                      // 63504 floats, fits in w region
    // total ws usage ~143 MB

    split_x_kernel<<<dim3(16, 128, 4), 256, 0, stream>>>(x, xhp, xlp);
    split_w_kernel<<<(9*CO*256)/256, 256, 0, stream>>>(conv_w, whT, wlT);

    conv_mfma_kernel<<<dim3(2, 32, N), 512, 0, stream>>>(xhp, whT, sigma);

    stats_kernel<<<CO, 1024, 0, stream>>>(sigma, gamma, beta, coef);

    fuse_kernel<<<N * OH, 512, 0, stream>>>(x, sigma, coef, outlo, sums);

    upsample_kernel<<<(N * C * H * W) / 256, 256, 0, stream>>>(outlo, sums, out);
}